// Round 6
// baseline (145.526 us; speedup 1.0000x reference)
//
#include <hip/hip_runtime.h>
#include <math.h>

#define F 256
#define E 256
#define S 32
#define CH 4
#define TLP 260   // tile row stride in uints: 1040 B -> 16B-aligned rows

typedef __attribute__((ext_vector_type(8))) short short8;
typedef __attribute__((ext_vector_type(4))) float f32x4;

__device__ __forceinline__ ushort f2bf(float x) {
    uint u = __float_as_uint(x);
    return (ushort)((u + 0x7fffu + ((u >> 16) & 1u)) >> 16);
}
__device__ __forceinline__ float bf2f(ushort h) {
    return __uint_as_float(((uint)h) << 16);
}
__device__ __forceinline__ uint4 pack8(const ushort* h) {
    uint4 r;
    r.x = (uint)h[0] | ((uint)h[1] << 16); r.y = (uint)h[2] | ((uint)h[3] << 16);
    r.z = (uint)h[4] | ((uint)h[5] << 16); r.w = (uint)h[6] | ((uint)h[7] << 16);
    return r;
}
__device__ __forceinline__ void split8(const float* x, short8& h, short8& l) {
    ushort hh[8], ll[8];
#pragma unroll
    for (int i = 0; i < 8; ++i) { hh[i] = f2bf(x[i]); ll[i] = f2bf(x[i] - bf2f(hh[i])); }
    uint4 ph = pack8(hh), pl = pack8(ll);
    h = *reinterpret_cast<short8*>(&ph);
    l = *reinterpret_cast<short8*>(&pl);
}
__device__ __forceinline__ short8 mk8(uint a, uint b, uint c, uint d) {
    uint4 p = make_uint4(a, b, c, d);
    return *reinterpret_cast<short8*>(&p);
}
__device__ __forceinline__ uint pkbf(float v) {
    const ushort h = f2bf(v);
    const ushort l = f2bf(v - bf2f(h));
    return (uint)h | ((uint)l << 16);
}

// ---------------------------------------------------------------------------
// prep: blocks 0..3   -> MT tile (64 rows): MT[j][i] = Wk_j . Wq_i, bf16x3
//                        MFMA straight from global (no LDS), output split hi/lo
//        blocks 4..19 -> WvT[j][k] = Wv[k][j], split hi/lo (LDS transpose)
//        blocks 20..23-> c[j] = Wk_j . bq (butterfly)
// ---------------------------------------------------------------------------
__global__ __launch_bounds__(512) void prep(const float* __restrict__ Wq,
                                            const float* __restrict__ bq,
                                            const float* __restrict__ Wk,
                                            const float* __restrict__ Wv,
                                            ushort* __restrict__ MTh,
                                            ushort* __restrict__ MTl,
                                            ushort* __restrict__ WvTh,
                                            ushort* __restrict__ WvTl,
                                            float* __restrict__ c) {
    const int blk = blockIdx.x, tid = threadIdx.x;
    const int lane = tid & 63, wave = tid >> 6;
    if (blk < 4) {
        const int wm = wave >> 2, wn = wave & 3;
        const int fr = lane & 15, fk = lane >> 4;
        const int j0 = blk * 64;
        f32x4 acc[2][4];
#pragma unroll
        for (int m = 0; m < 2; ++m)
#pragma unroll
            for (int n = 0; n < 4; ++n) acc[m][n] = (f32x4){0.f, 0.f, 0.f, 0.f};
        for (int k0 = 0; k0 < F; k0 += 32) {
            short8 ah[2], al[2];
#pragma unroll
            for (int m = 0; m < 2; ++m) {
                const float* p = &Wk[(size_t)(j0 + wm * 32 + m * 16 + fr) * F + k0 + fk * 8];
                float x[8];
                *reinterpret_cast<float4*>(&x[0]) = *reinterpret_cast<const float4*>(p);
                *reinterpret_cast<float4*>(&x[4]) = *reinterpret_cast<const float4*>(p + 4);
                split8(x, ah[m], al[m]);
            }
#pragma unroll
            for (int n = 0; n < 4; ++n) {
                const float* p = &Wq[(size_t)(wn * 64 + n * 16 + fr) * F + k0 + fk * 8];
                float x[8];
                *reinterpret_cast<float4*>(&x[0]) = *reinterpret_cast<const float4*>(p);
                *reinterpret_cast<float4*>(&x[4]) = *reinterpret_cast<const float4*>(p + 4);
                short8 bh, bl;
                split8(x, bh, bl);
#pragma unroll
                for (int m = 0; m < 2; ++m) {
                    acc[m][n] = __builtin_amdgcn_mfma_f32_16x16x32_bf16(ah[m], bh, acc[m][n], 0, 0, 0);
                    acc[m][n] = __builtin_amdgcn_mfma_f32_16x16x32_bf16(ah[m], bl, acc[m][n], 0, 0, 0);
                    acc[m][n] = __builtin_amdgcn_mfma_f32_16x16x32_bf16(al[m], bh, acc[m][n], 0, 0, 0);
                }
            }
        }
#pragma unroll
        for (int n = 0; n < 4; ++n) {
            const int i = wn * 64 + n * 16 + fr;
#pragma unroll
            for (int m = 0; m < 2; ++m)
#pragma unroll
                for (int r = 0; r < 4; ++r) {
                    const int j = j0 + wm * 32 + m * 16 + fk * 4 + r;
                    const float v = acc[m][n][r];
                    const ushort h = f2bf(v);
                    MTh[(size_t)j * F + i] = h;
                    MTl[(size_t)j * F + i] = f2bf(v - bf2f(h));
                }
        }
    } else if (blk < 20) {
        __shared__ float t[64][65];
        const int tb = blk - 4;
        const int jt = (tb & 3) * 64, kt = (tb >> 2) * 64;
        const int lk = tid >> 3, lj = (tid & 7) * 8;
        {
            const float* p = &Wv[(size_t)(kt + lk) * E + jt + lj];
            const float4 v0 = *reinterpret_cast<const float4*>(p);
            const float4 v1 = *reinterpret_cast<const float4*>(p + 4);
            t[lk][lj + 0] = v0.x; t[lk][lj + 1] = v0.y; t[lk][lj + 2] = v0.z; t[lk][lj + 3] = v0.w;
            t[lk][lj + 4] = v1.x; t[lk][lj + 5] = v1.y; t[lk][lj + 6] = v1.z; t[lk][lj + 7] = v1.w;
        }
        __syncthreads();
        const int oj = tid >> 3, ok = (tid & 7) * 8;
        ushort h[8], l[8];
#pragma unroll
        for (int u = 0; u < 8; ++u) {
            const float v = t[ok + u][oj];
            h[u] = f2bf(v); l[u] = f2bf(v - bf2f(h[u]));
        }
        *reinterpret_cast<uint4*>(&WvTh[(size_t)(jt + oj) * F + kt + ok]) = pack8(h);
        *reinterpret_cast<uint4*>(&WvTl[(size_t)(jt + oj) * F + kt + ok]) = pack8(l);
    } else {
        __shared__ float bqs[F];
        if (tid < F) bqs[tid] = bq[tid];
        __syncthreads();
        const float4 b4 = *reinterpret_cast<const float4*>(&bqs[lane * 4]);
#pragma unroll
        for (int i = 0; i < 8; ++i) {
            const int j = (blk - 20) * 64 + wave * 8 + i;
            const float4 k4 = *reinterpret_cast<const float4*>(&Wk[(size_t)j * F + lane * 4]);
            float p = k4.x * b4.x + k4.y * b4.y + k4.z * b4.z + k4.w * b4.w;
#pragma unroll
            for (int off = 32; off; off >>= 1) p += __shfl_xor(p, off);
            if (lane == 0) c[j] = p;
        }
    }
}

// ---------------------------------------------------------------------------
// attn helpers (proven online-softmax gather, R3)
// ---------------------------------------------------------------------------
__device__ __forceinline__ void ld_chunk(float4* d, int idxv, int s0,
                                         const float* __restrict__ t, int lane) {
#pragma unroll
    for (int j = 0; j < CH; ++j) {
        const int nid = __builtin_amdgcn_readlane(idxv, s0 + j);
        d[j] = *reinterpret_cast<const float4*>(&t[(size_t)nid * F + lane * 4]);
    }
}
__device__ __forceinline__ void proc_chunk(const float4* v, const float4 qv,
                                           float& m, float& l, float4& acc) {
#pragma unroll
    for (int j = 0; j < CH; ++j) {
        float p = v[j].x * qv.x + v[j].y * qv.y + v[j].z * qv.z + v[j].w * qv.w;
#pragma unroll
        for (int off = 32; off; off >>= 1) p += __shfl_xor(p, off);
        if (p <= m) {
            const float w = __expf(p - m);
            l += w;
            acc.x += w * v[j].x; acc.y += w * v[j].y;
            acc.z += w * v[j].z; acc.w += w * v[j].w;
        } else {
            const float cc = __expf(m - p);
            l = l * cc + 1.f;
            acc.x = acc.x * cc + v[j].x; acc.y = acc.y * cc + v[j].y;
            acc.z = acc.z * cc + v[j].z; acc.w = acc.w * cc + v[j].w;
            m = p;
        }
    }
}

// ---------------------------------------------------------------------------
// fused: one block = 64 nodes, 512 thr = 8 waves (2M x 4N).
// Phase B: q~ = gather(id2feat,nodes) @ MT + c  (bf16x3 MFMA, fragments read
//          straight from global/L2 - no LDS staging, no barriers) -> LDS tile
// Phase A: online-softmax neighbor gather (q from tile, m -> tile, packed
//          bf16 hi|lo per uint)
// Phase D: out = m @ WvT + bv (A-fragments unpacked from tile)
// ---------------------------------------------------------------------------
__global__ __launch_bounds__(512, 4) void fused(const int* __restrict__ nodes,
                                                const int* __restrict__ neigh,
                                                const float* __restrict__ id2feat,
                                                const ushort* __restrict__ MTh,
                                                const ushort* __restrict__ MTl,
                                                const ushort* __restrict__ WvTh,
                                                const ushort* __restrict__ WvTl,
                                                const float* __restrict__ cb,
                                                const float* __restrict__ bv,
                                                float* __restrict__ out,
                                                int B) {
    __shared__ uint tile[64][TLP];   // q~ f32 bits -> m packed (hi|lo) bf16

    const int tid = threadIdx.x;
    const int lane = tid & 63, wave = tid >> 6;
    const int wm = wave >> 2, wn = wave & 3;
    const int fr = lane & 15, fk = lane >> 4;
    const int row0 = blockIdx.x * 64;

    // ---------------- phase B ----------------
    int arow[2];
#pragma unroll
    for (int m = 0; m < 2; ++m) {
        const int r = row0 + wm * 32 + m * 16 + fr;
        arow[m] = nodes[r < B ? r : B - 1];
    }
    f32x4 acc[2][4];
#pragma unroll
    for (int m = 0; m < 2; ++m)
#pragma unroll
        for (int n = 0; n < 4; ++n) acc[m][n] = (f32x4){0.f, 0.f, 0.f, 0.f};

    for (int k0 = 0; k0 < F; k0 += 32) {
        short8 ah[2], al[2];
#pragma unroll
        for (int m = 0; m < 2; ++m) {
            const float* p = id2feat + (size_t)arow[m] * F + k0 + fk * 8;
            float x[8];
            *reinterpret_cast<float4*>(&x[0]) = *reinterpret_cast<const float4*>(p);
            *reinterpret_cast<float4*>(&x[4]) = *reinterpret_cast<const float4*>(p + 4);
            split8(x, ah[m], al[m]);
        }
#pragma unroll
        for (int n = 0; n < 4; ++n) {
            const size_t boff = (size_t)(wn * 64 + n * 16 + fr) * F + k0 + fk * 8;
            const short8 bh = *reinterpret_cast<const short8*>(&MTh[boff]);
            const short8 bl = *reinterpret_cast<const short8*>(&MTl[boff]);
#pragma unroll
            for (int m = 0; m < 2; ++m) {
                acc[m][n] = __builtin_amdgcn_mfma_f32_16x16x32_bf16(ah[m], bh, acc[m][n], 0, 0, 0);
                acc[m][n] = __builtin_amdgcn_mfma_f32_16x16x32_bf16(ah[m], bl, acc[m][n], 0, 0, 0);
                acc[m][n] = __builtin_amdgcn_mfma_f32_16x16x32_bf16(al[m], bh, acc[m][n], 0, 0, 0);
            }
        }
    }
    // write q~ (+c) into tile as f32 bits
#pragma unroll
    for (int n = 0; n < 4; ++n) {
        const int col = wn * 64 + n * 16 + fr;
        const float cc = cb[col];
#pragma unroll
        for (int m = 0; m < 2; ++m)
#pragma unroll
            for (int r = 0; r < 4; ++r)
                tile[wm * 32 + m * 16 + fk * 4 + r][col] = __float_as_uint(acc[m][n][r] + cc);
    }
    __syncthreads();

    // ---------------- phase attn ----------------
#pragma unroll 1
    for (int i = 0; i < 8; ++i) {
        const int tr = wave * 8 + i;
        const int node = row0 + tr;
        if (node < B) {
            const int idxv = neigh[node * S + (lane & (S - 1))];
            const uint4 q4 = *reinterpret_cast<const uint4*>(&tile[tr][lane * 4]);
            const float4 qv = make_float4(__uint_as_float(q4.x), __uint_as_float(q4.y),
                                          __uint_as_float(q4.z), __uint_as_float(q4.w));
            float m = -INFINITY, l = 0.f;
            float4 a = make_float4(0.f, 0.f, 0.f, 0.f);
            float4 va[CH], vb[CH];
            ld_chunk(va, idxv, 0, id2feat, lane);
            ld_chunk(vb, idxv, 4, id2feat, lane);
            proc_chunk(va, qv, m, l, a);
            ld_chunk(va, idxv, 8, id2feat, lane);
            proc_chunk(vb, qv, m, l, a);
            ld_chunk(vb, idxv, 12, id2feat, lane);
            proc_chunk(va, qv, m, l, a);
            ld_chunk(va, idxv, 16, id2feat, lane);
            proc_chunk(vb, qv, m, l, a);
            ld_chunk(vb, idxv, 20, id2feat, lane);
            proc_chunk(va, qv, m, l, a);
            ld_chunk(va, idxv, 24, id2feat, lane);
            proc_chunk(vb, qv, m, l, a);
            ld_chunk(vb, idxv, 28, id2feat, lane);
            proc_chunk(va, qv, m, l, a);
            proc_chunk(vb, qv, m, l, a);
            const float inv = 1.0f / l;
            const uint4 o = make_uint4(pkbf(a.x * inv), pkbf(a.y * inv),
                                       pkbf(a.z * inv), pkbf(a.w * inv));
            *reinterpret_cast<uint4*>(&tile[tr][lane * 4]) = o;
        }
    }
    __syncthreads();

    // ---------------- phase D ----------------
#pragma unroll
    for (int m = 0; m < 2; ++m)
#pragma unroll
        for (int n = 0; n < 4; ++n) acc[m][n] = (f32x4){0.f, 0.f, 0.f, 0.f};

    for (int k0 = 0; k0 < F; k0 += 32) {
        short8 ah[2], al[2];
#pragma unroll
        for (int m = 0; m < 2; ++m) {
            const int tr = wm * 32 + m * 16 + fr;
            const uint4 u0 = *reinterpret_cast<const uint4*>(&tile[tr][k0 + fk * 8]);
            const uint4 u1 = *reinterpret_cast<const uint4*>(&tile[tr][k0 + fk * 8 + 4]);
            ah[m] = mk8((u0.x & 0xffffu) | (u0.y << 16), (u0.z & 0xffffu) | (u0.w << 16),
                        (u1.x & 0xffffu) | (u1.y << 16), (u1.z & 0xffffu) | (u1.w << 16));
            al[m] = mk8((u0.x >> 16) | (u0.y & 0xffff0000u), (u0.z >> 16) | (u0.w & 0xffff0000u),
                        (u1.x >> 16) | (u1.y & 0xffff0000u), (u1.z >> 16) | (u1.w & 0xffff0000u));
        }
#pragma unroll
        for (int n = 0; n < 4; ++n) {
            const size_t boff = (size_t)(wn * 64 + n * 16 + fr) * F + k0 + fk * 8;
            const short8 bh = *reinterpret_cast<const short8*>(&WvTh[boff]);
            const short8 bl = *reinterpret_cast<const short8*>(&WvTl[boff]);
#pragma unroll
            for (int m = 0; m < 2; ++m) {
                acc[m][n] = __builtin_amdgcn_mfma_f32_16x16x32_bf16(ah[m], bh, acc[m][n], 0, 0, 0);
                acc[m][n] = __builtin_amdgcn_mfma_f32_16x16x32_bf16(ah[m], bl, acc[m][n], 0, 0, 0);
                acc[m][n] = __builtin_amdgcn_mfma_f32_16x16x32_bf16(al[m], bh, acc[m][n], 0, 0, 0);
            }
        }
    }
#pragma unroll
    for (int n = 0; n < 4; ++n) {
        const int col = wn * 64 + n * 16 + fr;
        const float bb = bv[col];
#pragma unroll
        for (int m = 0; m < 2; ++m)
#pragma unroll
            for (int r = 0; r < 4; ++r) {
                const int grow = row0 + wm * 32 + m * 16 + fk * 4 + r;
                if (grow < B) out[(size_t)grow * E + col] = acc[m][n][r] + bb;
            }
    }
}

// ---------------------------------------------------------------------------
extern "C" void kernel_launch(void* const* d_in, const int* in_sizes, int n_in,
                              void* d_out, int out_size, void* d_ws, size_t ws_size,
                              hipStream_t stream) {
    const int*   nodes   = (const int*)d_in[0];
    const int*   neigh   = (const int*)d_in[1];
    const float* id2feat = (const float*)d_in[2];
    const float* Wq      = (const float*)d_in[3];
    const float* bq      = (const float*)d_in[4];
    const float* Wk      = (const float*)d_in[5];
    // d_in[6] = bk unused: softmax-invariant (self column masked).
    const float* Wv      = (const float*)d_in[7];
    const float* bv      = (const float*)d_in[8];
    float* out = (float*)d_out;
    const int B = in_sizes[0];

    ushort* MTh  = (ushort*)d_ws;            // 65536 ushorts each
    ushort* MTl  = MTh + 65536;
    ushort* WvTh = MTl + 65536;
    ushort* WvTl = WvTh + 65536;
    float*  cbuf = (float*)(WvTl + 65536);   // 256 f32

    prep<<<dim3(24), dim3(512), 0, stream>>>(Wq, bq, Wk, Wv, MTh, MTl, WvTh, WvTl, cbuf);
    fused<<<dim3((B + 63) / 64), dim3(512), 0, stream>>>(nodes, neigh, id2feat,
                                                         MTh, MTl, WvTh, WvTl,
                                                         cbuf, bv, out, B);
}

// Round 7
// 124.685 us; speedup vs baseline: 1.1672x; 1.1672x over previous
//
#include <hip/hip_runtime.h>
#include <math.h>

#define F 256
#define E 256
#define S 32
#define CH 4
#define NB 16     // nodes per fused block
#define TLP 260   // tile row stride in uints: 1040 B, 16B-aligned rows

typedef __attribute__((ext_vector_type(8))) short short8;
typedef __attribute__((ext_vector_type(4))) float f32x4;

__device__ __forceinline__ ushort f2bf(float x) {
    uint u = __float_as_uint(x);
    return (ushort)((u + 0x7fffu + ((u >> 16) & 1u)) >> 16);
}
__device__ __forceinline__ float bf2f(ushort h) {
    return __uint_as_float(((uint)h) << 16);
}
__device__ __forceinline__ uint4 pack8(const ushort* h) {
    uint4 r;
    r.x = (uint)h[0] | ((uint)h[1] << 16); r.y = (uint)h[2] | ((uint)h[3] << 16);
    r.z = (uint)h[4] | ((uint)h[5] << 16); r.w = (uint)h[6] | ((uint)h[7] << 16);
    return r;
}
__device__ __forceinline__ void split8(const float* x, short8& h, short8& l) {
    ushort hh[8], ll[8];
#pragma unroll
    for (int i = 0; i < 8; ++i) { hh[i] = f2bf(x[i]); ll[i] = f2bf(x[i] - bf2f(hh[i])); }
    uint4 ph = pack8(hh), pl = pack8(ll);
    h = *reinterpret_cast<short8*>(&ph);
    l = *reinterpret_cast<short8*>(&pl);
}
__device__ __forceinline__ short8 mk8(uint a, uint b, uint c, uint d) {
    uint4 p = make_uint4(a, b, c, d);
    return *reinterpret_cast<short8*>(&p);
}
__device__ __forceinline__ uint pkbf(float v) {
    const ushort h = f2bf(v);
    const ushort l = f2bf(v - bf2f(h));
    return (uint)h | ((uint)l << 16);
}

// ---------------------------------------------------------------------------
// prep (unchanged from R5): blocks 0..3  -> MT[j][i] = Wk_j . Wq_i (bf16x3
// MFMA straight from global), split hi/lo; blocks 4..19 -> WvT transpose/split;
// blocks 20..23 -> c[j] = Wk_j . bq.
// ---------------------------------------------------------------------------
__global__ __launch_bounds__(512) void prep(const float* __restrict__ Wq,
                                            const float* __restrict__ bq,
                                            const float* __restrict__ Wk,
                                            const float* __restrict__ Wv,
                                            ushort* __restrict__ MTh,
                                            ushort* __restrict__ MTl,
                                            ushort* __restrict__ WvTh,
                                            ushort* __restrict__ WvTl,
                                            float* __restrict__ c) {
    const int blk = blockIdx.x, tid = threadIdx.x;
    const int lane = tid & 63, wave = tid >> 6;
    if (blk < 4) {
        const int wm = wave >> 2, wn = wave & 3;
        const int fr = lane & 15, fk = lane >> 4;
        const int j0 = blk * 64;
        f32x4 acc[2][4];
#pragma unroll
        for (int m = 0; m < 2; ++m)
#pragma unroll
            for (int n = 0; n < 4; ++n) acc[m][n] = (f32x4){0.f, 0.f, 0.f, 0.f};
        for (int k0 = 0; k0 < F; k0 += 32) {
            short8 ah[2], al[2];
#pragma unroll
            for (int m = 0; m < 2; ++m) {
                const float* p = &Wk[(size_t)(j0 + wm * 32 + m * 16 + fr) * F + k0 + fk * 8];
                float x[8];
                *reinterpret_cast<float4*>(&x[0]) = *reinterpret_cast<const float4*>(p);
                *reinterpret_cast<float4*>(&x[4]) = *reinterpret_cast<const float4*>(p + 4);
                split8(x, ah[m], al[m]);
            }
#pragma unroll
            for (int n = 0; n < 4; ++n) {
                const float* p = &Wq[(size_t)(wn * 64 + n * 16 + fr) * F + k0 + fk * 8];
                float x[8];
                *reinterpret_cast<float4*>(&x[0]) = *reinterpret_cast<const float4*>(p);
                *reinterpret_cast<float4*>(&x[4]) = *reinterpret_cast<const float4*>(p + 4);
                short8 bh, bl;
                split8(x, bh, bl);
#pragma unroll
                for (int m = 0; m < 2; ++m) {
                    acc[m][n] = __builtin_amdgcn_mfma_f32_16x16x32_bf16(ah[m], bh, acc[m][n], 0, 0, 0);
                    acc[m][n] = __builtin_amdgcn_mfma_f32_16x16x32_bf16(ah[m], bl, acc[m][n], 0, 0, 0);
                    acc[m][n] = __builtin_amdgcn_mfma_f32_16x16x32_bf16(al[m], bh, acc[m][n], 0, 0, 0);
                }
            }
        }
#pragma unroll
        for (int n = 0; n < 4; ++n) {
            const int i = wn * 64 + n * 16 + fr;
#pragma unroll
            for (int m = 0; m < 2; ++m)
#pragma unroll
                for (int r = 0; r < 4; ++r) {
                    const int j = j0 + wm * 32 + m * 16 + fk * 4 + r;
                    const float v = acc[m][n][r];
                    const ushort h = f2bf(v);
                    MTh[(size_t)j * F + i] = h;
                    MTl[(size_t)j * F + i] = f2bf(v - bf2f(h));
                }
        }
    } else if (blk < 20) {
        __shared__ float t[64][65];
        const int tb = blk - 4;
        const int jt = (tb & 3) * 64, kt = (tb >> 2) * 64;
        const int lk = tid >> 3, lj = (tid & 7) * 8;
        {
            const float* p = &Wv[(size_t)(kt + lk) * E + jt + lj];
            const float4 v0 = *reinterpret_cast<const float4*>(p);
            const float4 v1 = *reinterpret_cast<const float4*>(p + 4);
            t[lk][lj + 0] = v0.x; t[lk][lj + 1] = v0.y; t[lk][lj + 2] = v0.z; t[lk][lj + 3] = v0.w;
            t[lk][lj + 4] = v1.x; t[lk][lj + 5] = v1.y; t[lk][lj + 6] = v1.z; t[lk][lj + 7] = v1.w;
        }
        __syncthreads();
        const int oj = tid >> 3, ok = (tid & 7) * 8;
        ushort h[8], l[8];
#pragma unroll
        for (int u = 0; u < 8; ++u) {
            const float v = t[ok + u][oj];
            h[u] = f2bf(v); l[u] = f2bf(v - bf2f(h[u]));
        }
        *reinterpret_cast<uint4*>(&WvTh[(size_t)(jt + oj) * F + kt + ok]) = pack8(h);
        *reinterpret_cast<uint4*>(&WvTl[(size_t)(jt + oj) * F + kt + ok]) = pack8(l);
    } else {
        __shared__ float bqs[F];
        if (tid < F) bqs[tid] = bq[tid];
        __syncthreads();
        const float4 b4 = *reinterpret_cast<const float4*>(&bqs[lane * 4]);
#pragma unroll
        for (int i = 0; i < 8; ++i) {
            const int j = (blk - 20) * 64 + wave * 8 + i;
            const float4 k4 = *reinterpret_cast<const float4*>(&Wk[(size_t)j * F + lane * 4]);
            float p = k4.x * b4.x + k4.y * b4.y + k4.z * b4.z + k4.w * b4.w;
#pragma unroll
            for (int off = 32; off; off >>= 1) p += __shfl_xor(p, off);
            if (lane == 0) c[j] = p;
        }
    }
}

// ---------------------------------------------------------------------------
// attn helpers (proven online-softmax gather, R3)
// ---------------------------------------------------------------------------
__device__ __forceinline__ void ld_chunk(float4* d, int idxv, int s0,
                                         const float* __restrict__ t, int lane) {
#pragma unroll
    for (int j = 0; j < CH; ++j) {
        const int nid = __builtin_amdgcn_readlane(idxv, s0 + j);
        d[j] = *reinterpret_cast<const float4*>(&t[(size_t)nid * F + lane * 4]);
    }
}
__device__ __forceinline__ void proc_chunk(const float4* v, const float4 qv,
                                           float& m, float& l, float4& acc) {
#pragma unroll
    for (int j = 0; j < CH; ++j) {
        float p = v[j].x * qv.x + v[j].y * qv.y + v[j].z * qv.z + v[j].w * qv.w;
#pragma unroll
        for (int off = 32; off; off >>= 1) p += __shfl_xor(p, off);
        if (p <= m) {
            const float w = __expf(p - m);
            l += w;
            acc.x += w * v[j].x; acc.y += w * v[j].y;
            acc.z += w * v[j].z; acc.w += w * v[j].w;
        } else {
            const float cc = __expf(m - p);
            l = l * cc + 1.f;
            acc.x = acc.x * cc + v[j].x; acc.y = acc.y * cc + v[j].y;
            acc.z = acc.z * cc + v[j].z; acc.w = acc.w * cc + v[j].w;
            m = p;
        }
    }
}

// ---------------------------------------------------------------------------
// fused v2: one block = 16 nodes, 256 thr = 4 waves -> grid 625 (all resident,
// every CU busy; blocks progress through phases independently so B/D MFMA
// work of some blocks overlaps the gather wall of others).
// Phase B: q~[16x256] = gather(id2feat,nodes) @ MT + c  (M=16 -> single
//          fragment row; A read straight from L2/L3, no LDS staging) -> tile
// Phase A: online-softmax neighbor gather (4 nodes/wave), m -> tile packed
// Phase D: out = m @ WvT + bv (A unpacked from tile)
// ---------------------------------------------------------------------------
__global__ __launch_bounds__(256) void fused(const int* __restrict__ nodes,
                                             const int* __restrict__ neigh,
                                             const float* __restrict__ id2feat,
                                             const ushort* __restrict__ MTh,
                                             const ushort* __restrict__ MTl,
                                             const ushort* __restrict__ WvTh,
                                             const ushort* __restrict__ WvTl,
                                             const float* __restrict__ cb,
                                             const float* __restrict__ bv,
                                             float* __restrict__ out,
                                             int B) {
    __shared__ uint tile[NB][TLP];   // q~ f32 bits -> m packed (hi|lo) bf16

    const int tid = threadIdx.x;
    const int lane = tid & 63, wave = tid >> 6;   // wave 0..3
    const int fr = lane & 15, fk = lane >> 4;
    const int row0 = blockIdx.x * NB;

    // ---------------- phase B ----------------
    const int gr = row0 + fr;
    const int arow = nodes[gr < B ? gr : B - 1];

    f32x4 acc[4];
#pragma unroll
    for (int n = 0; n < 4; ++n) acc[n] = (f32x4){0.f, 0.f, 0.f, 0.f};

    for (int k0 = 0; k0 < F; k0 += 32) {
        const float* p = id2feat + (size_t)arow * F + k0 + fk * 8;
        float x[8];
        *reinterpret_cast<float4*>(&x[0]) = *reinterpret_cast<const float4*>(p);
        *reinterpret_cast<float4*>(&x[4]) = *reinterpret_cast<const float4*>(p + 4);
        short8 ah, al;
        split8(x, ah, al);
#pragma unroll
        for (int n = 0; n < 4; ++n) {
            const size_t boff = (size_t)(wave * 64 + n * 16 + fr) * F + k0 + fk * 8;
            const short8 bh = *reinterpret_cast<const short8*>(&MTh[boff]);
            const short8 bl = *reinterpret_cast<const short8*>(&MTl[boff]);
            acc[n] = __builtin_amdgcn_mfma_f32_16x16x32_bf16(ah, bh, acc[n], 0, 0, 0);
            acc[n] = __builtin_amdgcn_mfma_f32_16x16x32_bf16(ah, bl, acc[n], 0, 0, 0);
            acc[n] = __builtin_amdgcn_mfma_f32_16x16x32_bf16(al, bh, acc[n], 0, 0, 0);
        }
    }
#pragma unroll
    for (int n = 0; n < 4; ++n) {
        const int col = wave * 64 + n * 16 + fr;
        const float cc = cb[col];
#pragma unroll
        for (int r = 0; r < 4; ++r)
            tile[fk * 4 + r][col] = __float_as_uint(acc[n][r] + cc);
    }
    __syncthreads();

    // ---------------- phase attn ----------------
#pragma unroll 1
    for (int i = 0; i < 4; ++i) {
        const int tr = wave * 4 + i;
        const int node = row0 + tr;
        if (node < B) {
            const int idxv = neigh[node * S + (lane & (S - 1))];
            const uint4 q4 = *reinterpret_cast<const uint4*>(&tile[tr][lane * 4]);
            const float4 qv = make_float4(__uint_as_float(q4.x), __uint_as_float(q4.y),
                                          __uint_as_float(q4.z), __uint_as_float(q4.w));
            float m = -INFINITY, l = 0.f;
            float4 a = make_float4(0.f, 0.f, 0.f, 0.f);
            float4 va[CH], vb[CH];
            ld_chunk(va, idxv, 0, id2feat, lane);
            ld_chunk(vb, idxv, 4, id2feat, lane);
            proc_chunk(va, qv, m, l, a);
            ld_chunk(va, idxv, 8, id2feat, lane);
            proc_chunk(vb, qv, m, l, a);
            ld_chunk(vb, idxv, 12, id2feat, lane);
            proc_chunk(va, qv, m, l, a);
            ld_chunk(va, idxv, 16, id2feat, lane);
            proc_chunk(vb, qv, m, l, a);
            ld_chunk(vb, idxv, 20, id2feat, lane);
            proc_chunk(va, qv, m, l, a);
            ld_chunk(va, idxv, 24, id2feat, lane);
            proc_chunk(vb, qv, m, l, a);
            ld_chunk(vb, idxv, 28, id2feat, lane);
            proc_chunk(va, qv, m, l, a);
            proc_chunk(vb, qv, m, l, a);
            const float inv = 1.0f / l;
            const uint4 o = make_uint4(pkbf(a.x * inv), pkbf(a.y * inv),
                                       pkbf(a.z * inv), pkbf(a.w * inv));
            *reinterpret_cast<uint4*>(&tile[tr][lane * 4]) = o;
        }
    }
    __syncthreads();

    // ---------------- phase D ----------------
#pragma unroll
    for (int n = 0; n < 4; ++n) acc[n] = (f32x4){0.f, 0.f, 0.f, 0.f};

    for (int k0 = 0; k0 < F; k0 += 32) {
        const uint4 u0 = *reinterpret_cast<const uint4*>(&tile[fr][k0 + fk * 8]);
        const uint4 u1 = *reinterpret_cast<const uint4*>(&tile[fr][k0 + fk * 8 + 4]);
        const short8 ah = mk8((u0.x & 0xffffu) | (u0.y << 16), (u0.z & 0xffffu) | (u0.w << 16),
                              (u1.x & 0xffffu) | (u1.y << 16), (u1.z & 0xffffu) | (u1.w << 16));
        const short8 al = mk8((u0.x >> 16) | (u0.y & 0xffff0000u), (u0.z >> 16) | (u0.w & 0xffff0000u),
                              (u1.x >> 16) | (u1.y & 0xffff0000u), (u1.z >> 16) | (u1.w & 0xffff0000u));
#pragma unroll
        for (int n = 0; n < 4; ++n) {
            const size_t boff = (size_t)(wave * 64 + n * 16 + fr) * F + k0 + fk * 8;
            const short8 bh = *reinterpret_cast<const short8*>(&WvTh[boff]);
            const short8 bl = *reinterpret_cast<const short8*>(&WvTl[boff]);
            acc[n] = __builtin_amdgcn_mfma_f32_16x16x32_bf16(ah, bh, acc[n], 0, 0, 0);
            acc[n] = __builtin_amdgcn_mfma_f32_16x16x32_bf16(ah, bl, acc[n], 0, 0, 0);
            acc[n] = __builtin_amdgcn_mfma_f32_16x16x32_bf16(al, bh, acc[n], 0, 0, 0);
        }
    }
#pragma unroll
    for (int n = 0; n < 4; ++n) {
        const int col = wave * 64 + n * 16 + fr;
        const float bb = bv[col];
#pragma unroll
        for (int r = 0; r < 4; ++r) {
            const int grow = row0 + fk * 4 + r;
            if (grow < B) out[(size_t)grow * E + col] = acc[n][r] + bb;
        }
    }
}

// ---------------------------------------------------------------------------
extern "C" void kernel_launch(void* const* d_in, const int* in_sizes, int n_in,
                              void* d_out, int out_size, void* d_ws, size_t ws_size,
                              hipStream_t stream) {
    const int*   nodes   = (const int*)d_in[0];
    const int*   neigh   = (const int*)d_in[1];
    const float* id2feat = (const float*)d_in[2];
    const float* Wq      = (const float*)d_in[3];
    const float* bq      = (const float*)d_in[4];
    const float* Wk      = (const float*)d_in[5];
    // d_in[6] = bk unused: softmax-invariant (self column masked).
    const float* Wv      = (const float*)d_in[7];
    const float* bv      = (const float*)d_in[8];
    float* out = (float*)d_out;
    const int B = in_sizes[0];

    ushort* MTh  = (ushort*)d_ws;            // 65536 ushorts each
    ushort* MTl  = MTh + 65536;
    ushort* WvTh = MTl + 65536;
    ushort* WvTl = WvTh + 65536;
    float*  cbuf = (float*)(WvTl + 65536);   // 256 f32

    prep<<<dim3(24), dim3(512), 0, stream>>>(Wq, bq, Wk, Wv, MTh, MTl, WvTh, WvTl, cbuf);
    fused<<<dim3((B + NB - 1) / NB), dim3(256), 0, stream>>>(nodes, neigh, id2feat,
                                                             MTh, MTl, WvTh, WvTl,
                                                             cbuf, bv, out, B);
}

// Round 8
// 121.352 us; speedup vs baseline: 1.1992x; 1.0275x over previous
//
#include <hip/hip_runtime.h>
#include <math.h>

#define F 256
#define E 256
#define S 32
#define CH 4
#define NB 16     // nodes per fused block
#define TLP 260   // tile row stride in uints: 1040 B, 16B-aligned rows

typedef __attribute__((ext_vector_type(8))) short short8;
typedef __attribute__((ext_vector_type(4))) float f32x4;

__device__ __forceinline__ ushort f2bf(float x) {
    uint u = __float_as_uint(x);
    return (ushort)((u + 0x7fffu + ((u >> 16) & 1u)) >> 16);
}
__device__ __forceinline__ float bf2f(ushort h) {
    return __uint_as_float(((uint)h) << 16);
}
__device__ __forceinline__ uint4 pack8(const ushort* h) {
    uint4 r;
    r.x = (uint)h[0] | ((uint)h[1] << 16); r.y = (uint)h[2] | ((uint)h[3] << 16);
    r.z = (uint)h[4] | ((uint)h[5] << 16); r.w = (uint)h[6] | ((uint)h[7] << 16);
    return r;
}
__device__ __forceinline__ void split8(const float* x, short8& h, short8& l) {
    ushort hh[8], ll[8];
#pragma unroll
    for (int i = 0; i < 8; ++i) { hh[i] = f2bf(x[i]); ll[i] = f2bf(x[i] - bf2f(hh[i])); }
    uint4 ph = pack8(hh), pl = pack8(ll);
    h = *reinterpret_cast<short8*>(&ph);
    l = *reinterpret_cast<short8*>(&pl);
}
__device__ __forceinline__ short8 mk8(uint a, uint b, uint c, uint d) {
    uint4 p = make_uint4(a, b, c, d);
    return *reinterpret_cast<short8*>(&p);
}
__device__ __forceinline__ uint pkbf(float v) {
    const ushort h = f2bf(v);
    const ushort l = f2bf(v - bf2f(h));
    return (uint)h | ((uint)l << 16);
}

// ---------------------------------------------------------------------------
// prep (unchanged): blocks 0..3 -> MT[j][i] = Wk_j . Wq_i (bf16x3 MFMA from
// global), split hi/lo; blocks 4..19 -> WvT transpose/split; 20..23 -> c.
// ---------------------------------------------------------------------------
__global__ __launch_bounds__(512) void prep(const float* __restrict__ Wq,
                                            const float* __restrict__ bq,
                                            const float* __restrict__ Wk,
                                            const float* __restrict__ Wv,
                                            ushort* __restrict__ MTh,
                                            ushort* __restrict__ MTl,
                                            ushort* __restrict__ WvTh,
                                            ushort* __restrict__ WvTl,
                                            float* __restrict__ c) {
    const int blk = blockIdx.x, tid = threadIdx.x;
    const int lane = tid & 63, wave = tid >> 6;
    if (blk < 4) {
        const int wm = wave >> 2, wn = wave & 3;
        const int fr = lane & 15, fk = lane >> 4;
        const int j0 = blk * 64;
        f32x4 acc[2][4];
#pragma unroll
        for (int m = 0; m < 2; ++m)
#pragma unroll
            for (int n = 0; n < 4; ++n) acc[m][n] = (f32x4){0.f, 0.f, 0.f, 0.f};
        for (int k0 = 0; k0 < F; k0 += 32) {
            short8 ah[2], al[2];
#pragma unroll
            for (int m = 0; m < 2; ++m) {
                const float* p = &Wk[(size_t)(j0 + wm * 32 + m * 16 + fr) * F + k0 + fk * 8];
                float x[8];
                *reinterpret_cast<float4*>(&x[0]) = *reinterpret_cast<const float4*>(p);
                *reinterpret_cast<float4*>(&x[4]) = *reinterpret_cast<const float4*>(p + 4);
                split8(x, ah[m], al[m]);
            }
#pragma unroll
            for (int n = 0; n < 4; ++n) {
                const float* p = &Wq[(size_t)(wn * 64 + n * 16 + fr) * F + k0 + fk * 8];
                float x[8];
                *reinterpret_cast<float4*>(&x[0]) = *reinterpret_cast<const float4*>(p);
                *reinterpret_cast<float4*>(&x[4]) = *reinterpret_cast<const float4*>(p + 4);
                short8 bh, bl;
                split8(x, bh, bl);
#pragma unroll
                for (int m = 0; m < 2; ++m) {
                    acc[m][n] = __builtin_amdgcn_mfma_f32_16x16x32_bf16(ah[m], bh, acc[m][n], 0, 0, 0);
                    acc[m][n] = __builtin_amdgcn_mfma_f32_16x16x32_bf16(ah[m], bl, acc[m][n], 0, 0, 0);
                    acc[m][n] = __builtin_amdgcn_mfma_f32_16x16x32_bf16(al[m], bh, acc[m][n], 0, 0, 0);
                }
            }
        }
#pragma unroll
        for (int n = 0; n < 4; ++n) {
            const int i = wn * 64 + n * 16 + fr;
#pragma unroll
            for (int m = 0; m < 2; ++m)
#pragma unroll
                for (int r = 0; r < 4; ++r) {
                    const int j = j0 + wm * 32 + m * 16 + fk * 4 + r;
                    const float v = acc[m][n][r];
                    const ushort h = f2bf(v);
                    MTh[(size_t)j * F + i] = h;
                    MTl[(size_t)j * F + i] = f2bf(v - bf2f(h));
                }
        }
    } else if (blk < 20) {
        __shared__ float t[64][65];
        const int tb = blk - 4;
        const int jt = (tb & 3) * 64, kt = (tb >> 2) * 64;
        const int lk = tid >> 3, lj = (tid & 7) * 8;
        {
            const float* p = &Wv[(size_t)(kt + lk) * E + jt + lj];
            const float4 v0 = *reinterpret_cast<const float4*>(p);
            const float4 v1 = *reinterpret_cast<const float4*>(p + 4);
            t[lk][lj + 0] = v0.x; t[lk][lj + 1] = v0.y; t[lk][lj + 2] = v0.z; t[lk][lj + 3] = v0.w;
            t[lk][lj + 4] = v1.x; t[lk][lj + 5] = v1.y; t[lk][lj + 6] = v1.z; t[lk][lj + 7] = v1.w;
        }
        __syncthreads();
        const int oj = tid >> 3, ok = (tid & 7) * 8;
        ushort h[8], l[8];
#pragma unroll
        for (int u = 0; u < 8; ++u) {
            const float v = t[ok + u][oj];
            h[u] = f2bf(v); l[u] = f2bf(v - bf2f(h[u]));
        }
        *reinterpret_cast<uint4*>(&WvTh[(size_t)(jt + oj) * F + kt + ok]) = pack8(h);
        *reinterpret_cast<uint4*>(&WvTl[(size_t)(jt + oj) * F + kt + ok]) = pack8(l);
    } else {
        __shared__ float bqs[F];
        if (tid < F) bqs[tid] = bq[tid];
        __syncthreads();
        const float4 b4 = *reinterpret_cast<const float4*>(&bqs[lane * 4]);
#pragma unroll
        for (int i = 0; i < 8; ++i) {
            const int j = (blk - 20) * 64 + wave * 8 + i;
            const float4 k4 = *reinterpret_cast<const float4*>(&Wk[(size_t)j * F + lane * 4]);
            float p = k4.x * b4.x + k4.y * b4.y + k4.z * b4.z + k4.w * b4.w;
#pragma unroll
            for (int off = 32; off; off >>= 1) p += __shfl_xor(p, off);
            if (lane == 0) c[j] = p;
        }
    }
}

// ---------------------------------------------------------------------------
// attn helpers (proven online-softmax gather, R3)
// ---------------------------------------------------------------------------
__device__ __forceinline__ void ld_chunk(float4* d, int idxv, int s0,
                                         const float* __restrict__ t, int lane) {
#pragma unroll
    for (int j = 0; j < CH; ++j) {
        const int nid = __builtin_amdgcn_readlane(idxv, s0 + j);
        d[j] = *reinterpret_cast<const float4*>(&t[(size_t)nid * F + lane * 4]);
    }
}
__device__ __forceinline__ void proc_chunk(const float4* v, const float4 qv,
                                           float& m, float& l, float4& acc) {
#pragma unroll
    for (int j = 0; j < CH; ++j) {
        float p = v[j].x * qv.x + v[j].y * qv.y + v[j].z * qv.z + v[j].w * qv.w;
#pragma unroll
        for (int off = 32; off; off >>= 1) p += __shfl_xor(p, off);
        if (p <= m) {
            const float w = __expf(p - m);
            l += w;
            acc.x += w * v[j].x; acc.y += w * v[j].y;
            acc.z += w * v[j].z; acc.w += w * v[j].w;
        } else {
            const float cc = __expf(m - p);
            l = l * cc + 1.f;
            acc.x = acc.x * cc + v[j].x; acc.y = acc.y * cc + v[j].y;
            acc.z = acc.z * cc + v[j].z; acc.w = acc.w * cc + v[j].w;
            m = p;
        }
    }
}

// ---------------------------------------------------------------------------
// fused v3: one block = 16 nodes, 512 thr = 8 waves -> grid 625, ~19.5
// waves/CU (the standalone gather's operating point). Blocks progress through
// phases independently; B/D MFMA of some blocks overlaps others' gather wall.
// Phase B: q~[16x256] = gather @ MT + c (each wave 2 N-fragments) -> tile
// Phase A: online-softmax gather, 2 nodes/wave, m -> tile packed bf16 hi|lo
// Phase D: out = m @ WvT + bv (A unpacked from tile)
// ---------------------------------------------------------------------------
__global__ __launch_bounds__(512) void fused(const int* __restrict__ nodes,
                                             const int* __restrict__ neigh,
                                             const float* __restrict__ id2feat,
                                             const ushort* __restrict__ MTh,
                                             const ushort* __restrict__ MTl,
                                             const ushort* __restrict__ WvTh,
                                             const ushort* __restrict__ WvTl,
                                             const float* __restrict__ cb,
                                             const float* __restrict__ bv,
                                             float* __restrict__ out,
                                             int B) {
    __shared__ uint tile[NB][TLP];   // q~ f32 bits -> m packed (hi|lo) bf16

    const int tid = threadIdx.x;
    const int lane = tid & 63, wave = tid >> 6;   // wave 0..7
    const int fr = lane & 15, fk = lane >> 4;
    const int row0 = blockIdx.x * NB;

    // ---------------- phase B ----------------
    const int gr = row0 + fr;
    const int arow = nodes[gr < B ? gr : B - 1];

    f32x4 acc[2];
#pragma unroll
    for (int n = 0; n < 2; ++n) acc[n] = (f32x4){0.f, 0.f, 0.f, 0.f};

    for (int k0 = 0; k0 < F; k0 += 32) {
        const float* p = id2feat + (size_t)arow * F + k0 + fk * 8;
        float x[8];
        *reinterpret_cast<float4*>(&x[0]) = *reinterpret_cast<const float4*>(p);
        *reinterpret_cast<float4*>(&x[4]) = *reinterpret_cast<const float4*>(p + 4);
        short8 ah, al;
        split8(x, ah, al);
#pragma unroll
        for (int n = 0; n < 2; ++n) {
            const size_t boff = (size_t)(wave * 32 + n * 16 + fr) * F + k0 + fk * 8;
            const short8 bh = *reinterpret_cast<const short8*>(&MTh[boff]);
            const short8 bl = *reinterpret_cast<const short8*>(&MTl[boff]);
            acc[n] = __builtin_amdgcn_mfma_f32_16x16x32_bf16(ah, bh, acc[n], 0, 0, 0);
            acc[n] = __builtin_amdgcn_mfma_f32_16x16x32_bf16(ah, bl, acc[n], 0, 0, 0);
            acc[n] = __builtin_amdgcn_mfma_f32_16x16x32_bf16(al, bh, acc[n], 0, 0, 0);
        }
    }
#pragma unroll
    for (int n = 0; n < 2; ++n) {
        const int col = wave * 32 + n * 16 + fr;
        const float cc = cb[col];
#pragma unroll
        for (int r = 0; r < 4; ++r)
            tile[fk * 4 + r][col] = __float_as_uint(acc[n][r] + cc);
    }
    __syncthreads();

    // ---------------- phase attn (2 nodes per wave) ----------------
#pragma unroll 1
    for (int i = 0; i < 2; ++i) {
        const int tr = wave * 2 + i;
        const int node = row0 + tr;
        if (node < B) {
            const int idxv = neigh[node * S + (lane & (S - 1))];
            const uint4 q4 = *reinterpret_cast<const uint4*>(&tile[tr][lane * 4]);
            const float4 qv = make_float4(__uint_as_float(q4.x), __uint_as_float(q4.y),
                                          __uint_as_float(q4.z), __uint_as_float(q4.w));
            float m = -INFINITY, l = 0.f;
            float4 a = make_float4(0.f, 0.f, 0.f, 0.f);
            float4 va[CH], vb[CH];
            ld_chunk(va, idxv, 0, id2feat, lane);
            ld_chunk(vb, idxv, 4, id2feat, lane);
            proc_chunk(va, qv, m, l, a);
            ld_chunk(va, idxv, 8, id2feat, lane);
            proc_chunk(vb, qv, m, l, a);
            ld_chunk(vb, idxv, 12, id2feat, lane);
            proc_chunk(va, qv, m, l, a);
            ld_chunk(va, idxv, 16, id2feat, lane);
            proc_chunk(vb, qv, m, l, a);
            ld_chunk(vb, idxv, 20, id2feat, lane);
            proc_chunk(va, qv, m, l, a);
            ld_chunk(va, idxv, 24, id2feat, lane);
            proc_chunk(vb, qv, m, l, a);
            ld_chunk(vb, idxv, 28, id2feat, lane);
            proc_chunk(va, qv, m, l, a);
            proc_chunk(vb, qv, m, l, a);
            const float inv = 1.0f / l;
            const uint4 o = make_uint4(pkbf(a.x * inv), pkbf(a.y * inv),
                                       pkbf(a.z * inv), pkbf(a.w * inv));
            *reinterpret_cast<uint4*>(&tile[tr][lane * 4]) = o;
        }
    }
    __syncthreads();

    // ---------------- phase D ----------------
#pragma unroll
    for (int n = 0; n < 2; ++n) acc[n] = (f32x4){0.f, 0.f, 0.f, 0.f};

    for (int k0 = 0; k0 < F; k0 += 32) {
        const uint4 u0 = *reinterpret_cast<const uint4*>(&tile[fr][k0 + fk * 8]);
        const uint4 u1 = *reinterpret_cast<const uint4*>(&tile[fr][k0 + fk * 8 + 4]);
        const short8 ah = mk8((u0.x & 0xffffu) | (u0.y << 16), (u0.z & 0xffffu) | (u0.w << 16),
                              (u1.x & 0xffffu) | (u1.y << 16), (u1.z & 0xffffu) | (u1.w << 16));
        const short8 al = mk8((u0.x >> 16) | (u0.y & 0xffff0000u), (u0.z >> 16) | (u0.w & 0xffff0000u),
                              (u1.x >> 16) | (u1.y & 0xffff0000u), (u1.z >> 16) | (u1.w & 0xffff0000u));
#pragma unroll
        for (int n = 0; n < 2; ++n) {
            const size_t boff = (size_t)(wave * 32 + n * 16 + fr) * F + k0 + fk * 8;
            const short8 bh = *reinterpret_cast<const short8*>(&WvTh[boff]);
            const short8 bl = *reinterpret_cast<const short8*>(&WvTl[boff]);
            acc[n] = __builtin_amdgcn_mfma_f32_16x16x32_bf16(ah, bh, acc[n], 0, 0, 0);
            acc[n] = __builtin_amdgcn_mfma_f32_16x16x32_bf16(ah, bl, acc[n], 0, 0, 0);
            acc[n] = __builtin_amdgcn_mfma_f32_16x16x32_bf16(al, bh, acc[n], 0, 0, 0);
        }
    }
#pragma unroll
    for (int n = 0; n < 2; ++n) {
        const int col = wave * 32 + n * 16 + fr;
        const float bb = bv[col];
#pragma unroll
        for (int r = 0; r < 4; ++r) {
            const int grow = row0 + fk * 4 + r;
            if (grow < B) out[(size_t)grow * E + col] = acc[n][r] + bb;
        }
    }
}

// ---------------------------------------------------------------------------
extern "C" void kernel_launch(void* const* d_in, const int* in_sizes, int n_in,
                              void* d_out, int out_size, void* d_ws, size_t ws_size,
                              hipStream_t stream) {
    const int*   nodes   = (const int*)d_in[0];
    const int*   neigh   = (const int*)d_in[1];
    const float* id2feat = (const float*)d_in[2];
    const float* Wq      = (const float*)d_in[3];
    const float* bq      = (const float*)d_in[4];
    const float* Wk      = (const float*)d_in[5];
    // d_in[6] = bk unused: softmax-invariant (self column masked).
    const float* Wv      = (const float*)d_in[7];
    const float* bv      = (const float*)d_in[8];
    float* out = (float*)d_out;
    const int B = in_sizes[0];

    ushort* MTh  = (ushort*)d_ws;            // 65536 ushorts each
    ushort* MTl  = MTh + 65536;
    ushort* WvTh = MTl + 65536;
    ushort* WvTl = WvTh + 65536;
    float*  cbuf = (float*)(WvTl + 65536);   // 256 f32

    prep<<<dim3(24), dim3(512), 0, stream>>>(Wq, bq, Wk, Wv, MTh, MTl, WvTh, WvTl, cbuf);
    fused<<<dim3((B + NB - 1) / NB), dim3(512), 0, stream>>>(nodes, neigh, id2feat,
                                                             MTh, MTl, WvTh, WvTl,
                                                             cbuf, bv, out, B);
}